// Round 4
// baseline (513.944 us; speedup 1.0000x reference)
//
#include <hip/hip_runtime.h>
#include <stdint.h>

typedef short s8v __attribute__((ext_vector_type(8)));
typedef float f4v __attribute__((ext_vector_type(4)));
typedef unsigned short u16;

#define MFMA16(a, b, c) __builtin_amdgcn_mfma_f32_16x16x32_bf16(a, b, c, 0, 0, 0)
#define SCALE 0.1889822365046136f

__device__ __forceinline__ u16 f2bf(float f) {
  union { float f; uint32_t u; } v;
  v.f = f;
  uint32_t u = v.u;
  u += 0x7fffu + ((u >> 16) & 1u);   // RNE
  return (u16)(u >> 16);
}

__device__ __forceinline__ void gld_lds16(const void* g, void* l) {
  __builtin_amdgcn_global_load_lds(
      (const __attribute__((address_space(1))) void*)g,
      (__attribute__((address_space(3))) void*)l, 16, 0, 0);
}

// ---------------------------------------------------------------------------
// prep: weights only now (x cast fused into gemm1's A load).
// Pack W^T for QKV (768x224, zero-padded rows) and Wout (256x224, zero-padded
// rows) as bf16 [n][k] for the B^T-style MFMA GEMM.
// ---------------------------------------------------------------------------
__global__ void prep_kernel(const float* __restrict__ Wq,
                            const float* __restrict__ Wkv,
                            const float* __restrict__ Wout,
                            u16* __restrict__ wqkvt,
                            u16* __restrict__ woutt) {
  const int gsz = gridDim.x * blockDim.x;
  const int gt = blockIdx.x * blockDim.x + threadIdx.x;
  for (int i = gt; i < 768 * 224; i += gsz) {
    const int n = i / 224, k = i - n * 224;
    float v = 0.f;
    if (n < 224) v = Wq[k * 224 + n];
    else if (n < 672) v = Wkv[k * 448 + (n - 224)];
    wqkvt[i] = f2bf(v);
  }
  for (int i = gt; i < 256 * 224; i += gsz) {
    const int n = i / 224, k = i - n * 224;
    const float v = (n < 224) ? Wout[k * 224 + n] : 0.f;
    woutt[i] = f2bf(v);
  }
}

// ---------------------------------------------------------------------------
// A-in-register GEMM v4: C[M][N] = A[M][224] * Bt[N][224]^T.
// R3 analysis: LDS b128 read throughput (8 reads / 16 MFMA) was ~24 us/CU vs
// 4.7 us of MFMA — and the af half was the SAME data re-read per n-tile.
// Fix: each wave loads its 28 A-fragments (7 kt x 4 strips, 112 VGPR) ONCE,
// direct global->reg, reused across all NTILES n-tiles. A never touches LDS.
// A_F32: A is f32 (x input), cast to bf16 in-reg during the frag load
// (identical RNE + accumulation order as the old prep path).
// B: [128][32] subtiles, gld_lds double-buffer, distance-2, 1 barrier/step.
// LDS = 16 KB; VGPR ~215 (capped 256 via launch_bounds) -> 2 waves/SIMD.
// OUT_F32=0: store bf16. OUT_F32=1: store f32 + bias.
// ---------------------------------------------------------------------------
template <int A_F32, int OUT_F32, int NTILES>
__global__ __launch_bounds__(256, 2) void gemm_ar(const void* __restrict__ Ap,
                                                  const u16* __restrict__ Bt,
                                                  void* __restrict__ Cp,
                                                  const float* __restrict__ bias,
                                                  int Nvalid, int ldc) {
  extern __shared__ u16 smem[];
  u16* Bs0 = smem;            // [128][32] = 8192 B
  u16* Bs1 = smem + 4096;
  const int tid = threadIdx.x;
  const int wave = tid >> 6, lane = tid & 63;
  const int c16 = lane & 15, g = lane >> 4;
  const int m0 = blockIdx.x * 128;
  const int wm = wave & 1, wn = wave >> 1;

  // B staging geometry: subtile = 128 rows x 64 B; lane's byte = wave*1024+lane*16
  const int fbw = wave * 1024 + lane * 16;
  const int brow0 = fbw >> 6, bcol0 = (fbw & 63) >> 1;

#define STAGE_B(ntile, ktile, bufp)                                            \
  do {                                                                         \
    char* bb = (char*)((bufp) ? Bs1 : Bs0) + wave * 1024;                      \
    const u16* src =                                                           \
        Bt + (size_t)((ntile) * 128 + brow0) * 224 + (ktile) * 32 + bcol0;     \
    gld_lds16(src, bb);                                                        \
    gld_lds16(src + (size_t)64 * 224, bb + 4096);                              \
  } while (0)

  STAGE_B(0, 0, 0);          // step 0 -> buf0
  if (NTILES * 7 > 1) STAGE_B(0, 1, 1);   // step 1 -> buf1

  // ---- A fragments: global -> registers, once. 28 frags = 112 VGPR.
  // Frag (kt,t): rows wm*64 + t*16 + c16, cols kt*32 + g*8 .. +7.
  s8v af[7][4];
#pragma unroll
  for (int kt = 0; kt < 7; ++kt) {
#pragma unroll
    for (int t = 0; t < 4; ++t) {
      const int row = m0 + wm * 64 + t * 16 + c16;
      if (A_F32) {
        const float* ap = (const float*)Ap + (size_t)row * 224 + kt * 32 + g * 8;
        const float4 lo = *(const float4*)ap;
        const float4 hi = *(const float4*)(ap + 4);
        s8v v;
        v[0] = (short)f2bf(lo.x); v[1] = (short)f2bf(lo.y);
        v[2] = (short)f2bf(lo.z); v[3] = (short)f2bf(lo.w);
        v[4] = (short)f2bf(hi.x); v[5] = (short)f2bf(hi.y);
        v[6] = (short)f2bf(hi.z); v[7] = (short)f2bf(hi.w);
        af[kt][t] = v;
      } else {
        af[kt][t] = *(const s8v*)((const u16*)Ap + (size_t)row * 224 + kt * 32 + g * 8);
      }
    }
  }

  __syncthreads();           // drains af loads + B0 + B1

#pragma unroll
  for (int nt = 0; nt < NTILES; ++nt) {
    f4v acc[4][4] = {};
#pragma unroll
    for (int kt = 0; kt < 7; ++kt) {
      const int t = nt * 7 + kt;
      const u16* Bs = (t & 1) ? Bs1 : Bs0;
      s8v bf[4];
#pragma unroll
      for (int tt = 0; tt < 4; ++tt)
        bf[tt] = *(const s8v*)&Bs[(wn * 64 + tt * 16 + c16) * 32 + g * 8];
#pragma unroll
      for (int i = 0; i < 4; ++i)
#pragma unroll
        for (int j = 0; j < 4; ++j)
          acc[i][j] = MFMA16(af[kt][i], bf[j], acc[i][j]);
      __syncthreads();       // stage(t+1) already latency-covered; waves synced
      const int ns = t + 2;
      if (ns < NTILES * 7) {
        const int nnt = ns / 7;
        STAGE_B(nnt, ns - nnt * 7, t & 1);   // overwrite the buffer just read
      }
    }
    const int n0 = nt * 128;
#pragma unroll
    for (int i = 0; i < 4; ++i) {
      const int rowb = m0 + wm * 64 + i * 16 + g * 4;
#pragma unroll
      for (int j = 0; j < 4; ++j) {
        const int col = n0 + wn * 64 + j * 16 + c16;
        if (col < Nvalid) {
          if (OUT_F32) {
            const float bz = bias[col];
            for (int r = 0; r < 4; ++r)
              ((float*)Cp)[(size_t)(rowb + r) * ldc + col] = acc[i][j][r] + bz;
          } else {
            for (int r = 0; r < 4; ++r)
              ((u16*)Cp)[(size_t)(rowb + r) * ldc + col] = f2bf(acc[i][j][r]);
          }
        }
      }
    }
  }
#undef STAGE_B
}

// ---------------------------------------------------------------------------
// Branch 1: local window attention. One block per (b, window); wave = head.
// qkv layout: row = spatial index s in (b,32,32), 672 cols: q 0..223, k 224..447,
// v 448..671; branch-1 head h uses cols h*28..h*28+27 of each.
// LDS: qs/ks [4][64][32] (d padded to 32 w/ zeros), vt [4][32][72] = V^T,
// pm [4][64][72] (P in A-layout) aliased over qs+ks.
// ---------------------------------------------------------------------------
__global__ __launch_bounds__(256) void attn_local(const u16* __restrict__ qkv,
                                                  const float* __restrict__ pos1,
                                                  u16* __restrict__ attn) {
  extern __shared__ u16 sm[];
  u16* qs = sm;           // 8192 shorts
  u16* ks = sm + 8192;    // 8192 shorts
  u16* vt = sm + 18432;   // 9216 shorts, byte 36864..55295
  u16* pm = sm;           // 18432 shorts, aliases qs+ks (+3840B spare)
  const int blk = blockIdx.x;
  const int b = blk >> 4, win = blk & 15;
  const int wy = win >> 2, wx = win & 3;
  const int tid = threadIdx.x;
  const int base_s = (b * 32 + wy * 8) * 32 + wx * 8;
  // stage q,k (ushort4-vectorized, 28 = 7*4)
  for (int idx = tid; idx < 3584; idx += 256) {
    const int mtx = idx / 1792;
    int rem = idx - mtx * 1792;
    const int h = rem / 448; rem -= h * 448;
    const int t = rem / 7;
    const int c4 = rem - t * 7;
    const int s = base_s + (t >> 3) * 32 + (t & 7);
    const ushort4 v = *(const ushort4*)(qkv + (size_t)s * 672 + mtx * 224 + h * 28 + c4 * 4);
    *(ushort4*)((mtx ? ks : qs) + (h * 64 + t) * 32 + c4 * 4) = v;
  }
  // zero k-pad cols 28..31 of q,k
  for (int idx = tid; idx < 512; idx += 256) {
    const int mtx = idx >> 8;
    const int h = (idx >> 6) & 3, t = idx & 63;
    const ushort4 z = {0, 0, 0, 0};
    *(ushort4*)((mtx ? ks : qs) + (h * 64 + t) * 32 + 28) = z;
  }
  // stage v transposed -> vt[h][d][t] (rows 28..31 uninit: only feed masked cols)
  for (int idx = tid; idx < 1792; idx += 256) {
    const int h = idx / 448;
    int rem = idx - h * 448;
    const int t = rem / 7;
    const int c4 = rem - t * 7;
    const int s = base_s + (t >> 3) * 32 + (t & 7);
    const ushort4 v = *(const ushort4*)(qkv + (size_t)s * 672 + 448 + h * 28 + c4 * 4);
    u16* col = vt + (h * 32 + c4 * 4) * 72 + t;
    col[0] = v.x; col[72] = v.y; col[144] = v.z; col[216] = v.w;
  }
  __syncthreads();
  const int h = tid >> 6, lane = tid & 63;
  const int c16 = lane & 15, g = lane >> 4;
  s8v af[4], bf[4];
  for (int t = 0; t < 4; ++t) af[t] = *(const s8v*)&qs[(h * 64 + t * 16 + c16) * 32 + g * 8];
  for (int t = 0; t < 4; ++t) bf[t] = *(const s8v*)&ks[(h * 64 + t * 16 + c16) * 32 + g * 8];
  const f4v fz = {0.f, 0.f, 0.f, 0.f};
  f4v sc[4][4];
  for (int i = 0; i < 4; ++i)
    for (int j = 0; j < 4; ++j)
      sc[i][j] = MFMA16(af[i], bf[j], fz);
  // softmax: C layout row = g*4+reg (within 16-tile), col = c16; full row spans 4 j-tiles
  float lrow[4][4];
  const float* ph = pos1 + h * 4096;
  for (int i = 0; i < 4; ++i) {
    for (int r = 0; r < 4; ++r) {
      const int irow = i * 16 + g * 4 + r;
      float mx = -1e30f;
      for (int j = 0; j < 4; ++j) {
        const float v = sc[i][j][r] * SCALE + ph[irow * 64 + j * 16 + c16];
        sc[i][j][r] = v;
        mx = fmaxf(mx, v);
      }
      for (int d = 1; d < 16; d <<= 1) mx = fmaxf(mx, __shfl_xor(mx, d, 64));
      float sum = 0.f;
      for (int j = 0; j < 4; ++j) {
        const float e = __expf(sc[i][j][r] - mx);
        sc[i][j][r] = e;
        sum += e;
      }
      for (int d = 1; d < 16; d <<= 1) sum += __shfl_xor(sum, d, 64);
      lrow[i][r] = sum;
    }
  }
  __syncthreads();   // all qs/ks frag reads done before pm (aliased) is written
  for (int i = 0; i < 4; ++i)
    for (int r = 0; r < 4; ++r) {
      const int irow = i * 16 + g * 4 + r;
      for (int j = 0; j < 4; ++j)
        pm[(h * 64 + irow) * 72 + j * 16 + c16] = f2bf(sc[i][j][r]);
    }
  // PV: A = P rows [i][j], B = V^T rows [d][j]; K = 64 -> 2 iters
  f4v o[4][2] = {};
  for (int kk = 0; kk < 2; ++kk) {
    s8v ap[4], bv[2];
    for (int t = 0; t < 4; ++t)
      ap[t] = *(const s8v*)&pm[(h * 64 + t * 16 + c16) * 72 + kk * 32 + g * 8];
    for (int t = 0; t < 2; ++t)
      bv[t] = *(const s8v*)&vt[(h * 32 + t * 16 + c16) * 72 + kk * 32 + g * 8];
    for (int i = 0; i < 4; ++i)
      for (int j = 0; j < 2; ++j)
        o[i][j] = MFMA16(ap[i], bv[j], o[i][j]);
  }
  for (int i = 0; i < 4; ++i)
    for (int r = 0; r < 4; ++r) {
      const int irow = i * 16 + g * 4 + r;
      const int s = base_s + (irow >> 3) * 32 + (irow & 7);
      const float inv = 1.f / lrow[i][r];
      for (int j = 0; j < 2; ++j) {
        const int d = j * 16 + c16;
        if (d < 28)
          attn[(size_t)s * 224 + h * 28 + d] = f2bf(o[i][j][r] * inv);
      }
    }
}

// ---------------------------------------------------------------------------
// Branch 2 v2: cross-window attention, fully LDS-staged.
// Block = (b, group of 4 positions); wave w = position i = ig*4+w, loops 4 heads.
// One coalesced staging pass reads q2/k2/v2 rows (3 x 224B per spatial row,
// 64 rows) into LDS: qs/ks [w][h][j][32] (frag layout, d zero-padded),
// vt [w][h][d pad32][j] = V^T for the PV B-operand.
// LDS: qs 16K + ks 16K + vt 16K + p2 4K = 53248 B -> 3 blocks/CU.
// ---------------------------------------------------------------------------
__global__ __launch_bounds__(256) void attn_global(const u16* __restrict__ qkv,
                                                   const float* __restrict__ pos2,
                                                   u16* __restrict__ attn) {
  extern __shared__ u16 smg[];
  u16* qs = smg;            // [4][4][16][32] = 8192 u16
  u16* ks = smg + 8192;     // [4][4][16][32]
  u16* vt = smg + 16384;    // [4][4][32][16] = 8192 u16
  u16* p2 = smg + 24576;    // [4][16][32]    = 2048 u16
  const int blk = blockIdx.x;
  const int b = blk >> 4, ig = blk & 15;
  const int tid = threadIdx.x;
  // ---- staging: 3 segs x 64 (w,j) rows x 28 ushort4
  for (int idx = tid; idx < 5376; idx += 256) {
    const int seg = idx / 1792;
    int rem = idx - seg * 1792;
    const int row = rem / 28;
    const int c4 = rem - row * 28;
    const int w = row >> 4, j = row & 15;
    const int ii = ig * 4 + w;
    const int y = ii >> 3, x = ii & 7;
    const int s = (b * 32 + (j >> 2) * 8 + y) * 32 + (j & 3) * 8 + x;
    const int hq = c4 / 7, d4 = c4 - hq * 7;   // 28 = 4 heads x 7 ushort4
    const ushort4 v = *(const ushort4*)(qkv + (size_t)s * 672 + 112 + seg * 224 + c4 * 4);
    if (seg < 2) {
      *(ushort4*)((seg ? ks : qs) + ((w * 4 + hq) * 16 + j) * 32 + d4 * 4) = v;
    } else {
      u16* col = vt + ((w * 4 + hq) * 32 + d4 * 4) * 16 + j;
      col[0] = v.x; col[16] = v.y; col[32] = v.z; col[48] = v.w;
    }
  }
  // zero d-pad 28..31 of qs/ks (feeds MFMA K-dim) and vt rows 28..31
  for (int idx = tid; idx < 512; idx += 256) {
    const ushort4 z = {0, 0, 0, 0};
    *(ushort4*)(((idx & 256) ? ks : qs) + (idx & 255) * 32 + 28) = z;
  }
  {
    const ushort4 z = {0, 0, 0, 0};
    const int w = tid >> 6, hq = (tid >> 4) & 3;
    const int dd = 28 + ((tid >> 2) & 3), j4 = tid & 3;
    *(ushort4*)(vt + ((w * 4 + hq) * 32 + dd) * 16 + j4 * 4) = z;
  }
  __syncthreads();
  const int w = tid >> 6, lane = tid & 63;
  const int c16 = lane & 15, g = lane >> 4;
  const int i = ig * 4 + w;            // position within window
  const int y = i >> 3, x = i & 7;
  const int w4 = w * 4;
  const f4v fz = {0.f, 0.f, 0.f, 0.f};
  for (int h = 0; h < 4; ++h) {
    const s8v aq = *(const s8v*)&qs[((w4 + h) * 16 + c16) * 32 + g * 8];
    const s8v bk = *(const s8v*)&ks[((w4 + h) * 16 + c16) * 32 + g * 8];
    const f4v s = MFMA16(aq, bk, fz);
    const float* ph = pos2 + h * 256;
    float l[4];
    for (int r = 0; r < 4; ++r) {
      const float v = s[r] * SCALE + ph[(g * 4 + r) * 16 + c16];
      float mx = v;
      for (int d = 1; d < 16; d <<= 1) mx = fmaxf(mx, __shfl_xor(mx, d, 64));
      const float e = __expf(v - mx);
      float sum = e;
      for (int d = 1; d < 16; d <<= 1) sum += __shfl_xor(sum, d, 64);
      l[r] = sum;
      p2[(w * 16 + g * 4 + r) * 32 + c16] = f2bf(e);
      p2[(w * 16 + g * 4 + r) * 32 + c16 + 16] = 0;   // K pad 16..31
    }
    const s8v ap = *(const s8v*)&p2[(w * 16 + c16) * 32 + g * 8];  // same-wave RAW
    f4v o[2];
    for (int nt = 0; nt < 2; ++nt) {
      s8v bv = {0, 0, 0, 0, 0, 0, 0, 0};
      if (g < 2)   // K elems g*8..g*8+7 < 16 (j 16..31 have P == 0 anyway)
        bv = *(const s8v*)&vt[((w4 + h) * 32 + nt * 16 + c16) * 16 + g * 8];
      o[nt] = MFMA16(ap, bv, fz);
    }
    for (int nt = 0; nt < 2; ++nt)
      for (int r = 0; r < 4; ++r) {
        const int d = nt * 16 + c16;
        if (d < 28) {
          const int wi = g * 4 + r;
          const int sw = (b * 32 + (wi >> 2) * 8 + y) * 32 + (wi & 3) * 8 + x;
          attn[(size_t)sw * 224 + 112 + h * 28 + d] = f2bf(o[nt][r] / l[r]);
        }
      }
  }
}

// ---------------------------------------------------------------------------
// ws layout (bytes):
//   qkv   @ 0          : 131072*672*2 = 176,160,768
//   attn  @ 176160768  : 131072*224*2 =  58,720,256
//   wqkvt @ 234881024  : 768*224*2    =     344,064
//   woutt @ 235225088  : 256*224*2    =     114,688
// total ~224.5 MB
// ---------------------------------------------------------------------------
extern "C" void kernel_launch(void* const* d_in, const int* in_sizes, int n_in,
                              void* d_out, int out_size, void* d_ws, size_t ws_size,
                              hipStream_t stream) {
  const float* x    = (const float*)d_in[0];
  const float* Wq   = (const float*)d_in[1];
  const float* Wkv  = (const float*)d_in[2];
  const float* Wout = (const float*)d_in[3];
  const float* bout = (const float*)d_in[4];
  const float* pos1 = (const float*)d_in[5];
  const float* pos2 = (const float*)d_in[6];
  char* ws = (char*)d_ws;
  u16* qkv   = (u16*)ws;
  u16* attn  = (u16*)(ws + 176160768);
  u16* wqkvt = (u16*)(ws + 234881024);
  u16* woutt = (u16*)(ws + 235225088);

  prep_kernel<<<dim3(128), 256, 0, stream>>>(Wq, Wkv, Wout, wqkvt, woutt);

  // qkv = x @ [Wq|Wkv]  (A = x f32, cast fused; M=131072 -> 1024 tiles, N=672)
  gemm_ar<1, 0, 6><<<dim3(1024), 256, 16384, stream>>>(x, wqkvt, qkv, nullptr, 672, 672);

  attn_local<<<dim3(2048), 256, 55296, stream>>>(qkv, pos1, attn);
  attn_global<<<dim3(2048), 256, 53248, stream>>>(qkv, pos2, attn);

  // out = attn @ Wout + bout (A = attn bf16; f32 out, N=224 -> 2 n-tiles)
  gemm_ar<0, 1, 2><<<dim3(1024), 256, 16384, stream>>>(attn, woutt, d_out, bout, 224, 224);
}

// Round 5
// 429.718 us; speedup vs baseline: 1.1960x; 1.1960x over previous
//
#include <hip/hip_runtime.h>
#include <stdint.h>

typedef short s8v __attribute__((ext_vector_type(8)));
typedef float f4v __attribute__((ext_vector_type(4)));
typedef unsigned short u16;

#define MFMA16(a, b, c) __builtin_amdgcn_mfma_f32_16x16x32_bf16(a, b, c, 0, 0, 0)
#define SCALE 0.1889822365046136f

__device__ __forceinline__ u16 f2bf(float f) {
  union { float f; uint32_t u; } v;
  v.f = f;
  uint32_t u = v.u;
  u += 0x7fffu + ((u >> 16) & 1u);   // RNE
  return (u16)(u >> 16);
}

__device__ __forceinline__ void gld_lds16(const void* g, void* l) {
  __builtin_amdgcn_global_load_lds(
      (const __attribute__((address_space(1))) void*)g,
      (__attribute__((address_space(3))) void*)l, 16, 0, 0);
}

// ---------------------------------------------------------------------------
// prep: weights only (x cast fused into gemm1's A staging).
// Pack W^T for QKV (768x224, zero-padded rows) and Wout (256x224, zero-padded
// rows) as bf16 [n][k] for the B^T-style MFMA GEMM.
// ---------------------------------------------------------------------------
__global__ void prep_kernel(const float* __restrict__ Wq,
                            const float* __restrict__ Wkv,
                            const float* __restrict__ Wout,
                            u16* __restrict__ wqkvt,
                            u16* __restrict__ woutt) {
  const int gsz = gridDim.x * blockDim.x;
  const int gt = blockIdx.x * blockDim.x + threadIdx.x;
  for (int i = gt; i < 768 * 224; i += gsz) {
    const int n = i / 224, k = i - n * 224;
    float v = 0.f;
    if (n < 224) v = Wq[k * 224 + n];
    else if (n < 672) v = Wkv[k * 448 + (n - 224)];
    wqkvt[i] = f2bf(v);
  }
  for (int i = gt; i < 256 * 224; i += gsz) {
    const int n = i / 224, k = i - n * 224;
    const float v = (n < 224) ? Wout[k * 224 + n] : 0.f;
    woutt[i] = f2bf(v);
  }
}

// ---------------------------------------------------------------------------
// A-persistent GEMM (R3 structure): C[M][N] = A[M][224] * Bt[N][224]^T.
// 128-row M-tile, A (128x224 bf16, 56KB) staged once into LDS; block loops
// NTILES 128-wide n-tiles streaming B subtiles [128][32] (gld_lds dbuf,
// distance-2, one barrier per K-step).
// A_F32=1: A is f32 (the x input). Staging = coalesced float4 loads (28
//   rounds x 256 threads x 16B, consecutive), RNE cast in-reg, ds_write_b64
//   into the same As layout. Values + accumulation order identical to the
//   old prep path; deletes prep's 176MB x pass. (R4 lesson: A-reuse in LDS,
//   NOT in 112 VGPRs; A loads must stay coalesced.)
// A_F32=0: A already bf16 -> gld_lds16 14-round staging (R3 path).
// LDS = 57344 + 2*8192 = 73728 B -> 2 blocks/CU.
// OUT_F32=0: store bf16. OUT_F32=1: store f32 + bias.
// ---------------------------------------------------------------------------
template <int A_F32, int OUT_F32, int NTILES>
__global__ __launch_bounds__(256) void gemm_af(const void* __restrict__ Ap,
                                               const u16* __restrict__ Bt,
                                               void* __restrict__ Cp,
                                               const float* __restrict__ bias,
                                               int Nvalid, int ldc) {
  extern __shared__ u16 smem[];
  u16* As  = smem;            // [128][224] = 57344 B
  u16* Bs0 = smem + 28672;    // [128][32] = 8192 B
  u16* Bs1 = smem + 32768;
  const int tid = threadIdx.x;
  const int wave = tid >> 6, lane = tid & 63;
  const int c16 = lane & 15, g = lane >> 4;
  const int m0 = blockIdx.x * 128;
  const int wm = wave & 1, wn = wave >> 1;

  // B staging geometry: subtile = 128 rows x 64 B; lane's byte = wave*1024+lane*16
  const int fbw = wave * 1024 + lane * 16;
  const int brow0 = fbw >> 6, bcol0 = (fbw & 63) >> 1;

#define STAGE_B(ntile, ktile, bufp)                                            \
  do {                                                                         \
    char* bb = (char*)((bufp) ? Bs1 : Bs0) + wave * 1024;                      \
    const u16* src =                                                           \
        Bt + (size_t)((ntile) * 128 + brow0) * 224 + (ktile) * 32 + bcol0;     \
    gld_lds16(src, bb);                                                        \
    gld_lds16(src + (size_t)64 * 224, bb + 4096);                              \
  } while (0)

  STAGE_B(0, 0, 0);          // step 0 -> buf0  (B loads start first)
  if (NTILES * 7 > 1) STAGE_B(0, 1, 1);   // step 1 -> buf1

  // ---- stage full A tile once
  if (A_F32) {
    // 28 rounds: 256 threads x float4 (16B, coalesced) -> cast -> ds_write 8B
    const float* Af = (const float*)Ap + (size_t)m0 * 224;
#pragma unroll
    for (int rnd = 0; rnd < 28; ++rnd) {
      const int e0 = rnd * 1024 + tid * 4;   // element index in 128x224 tile
      const float4 v = *(const float4*)(Af + e0);
      ushort4 o;
      o.x = f2bf(v.x); o.y = f2bf(v.y); o.z = f2bf(v.z); o.w = f2bf(v.w);
      *(ushort4*)(As + e0) = o;
    }
  } else {
    // 14 rounds x (256 lanes x 16 B) via global_load_lds
    for (int rnd = 0; rnd < 14; ++rnd) {
      const int fb = rnd * 4096 + fbw;
      const int row = fb / 448;            // 448 B per A row
      const int off = fb - row * 448;
      gld_lds16((const u16*)Ap + (size_t)(m0 + row) * 224 + (off >> 1),
                (char*)As + rnd * 4096 + wave * 1024);
    }
  }

  __syncthreads();           // drains A (vm+lgkm) + B0 + B1

  for (int nt = 0; nt < NTILES; ++nt) {
    f4v acc[4][4] = {};
    for (int kt = 0; kt < 7; ++kt) {
      const int t = nt * 7 + kt;
      const u16* Bs = (t & 1) ? Bs1 : Bs0;
      s8v af[4], bf[4];
      for (int tt = 0; tt < 4; ++tt)
        af[tt] = *(const s8v*)&As[(wm * 64 + tt * 16 + c16) * 224 + kt * 32 + g * 8];
      for (int tt = 0; tt < 4; ++tt)
        bf[tt] = *(const s8v*)&Bs[(wn * 64 + tt * 16 + c16) * 32 + g * 8];
      for (int i = 0; i < 4; ++i)
        for (int j = 0; j < 4; ++j)
          acc[i][j] = MFMA16(af[i], bf[j], acc[i][j]);
      __syncthreads();       // stage(t+1) already latency-covered; waves synced
      const int ns = t + 2;
      if (ns < NTILES * 7) {
        const int nnt = ns / 7;
        STAGE_B(nnt, ns - nnt * 7, t & 1);   // overwrite the buffer just read
      }
    }
    const int n0 = nt * 128;
    for (int i = 0; i < 4; ++i) {
      const int rowb = m0 + wm * 64 + i * 16 + g * 4;
      for (int j = 0; j < 4; ++j) {
        const int col = n0 + wn * 64 + j * 16 + c16;
        if (col < Nvalid) {
          if (OUT_F32) {
            const float bz = bias[col];
            for (int r = 0; r < 4; ++r)
              ((float*)Cp)[(size_t)(rowb + r) * ldc + col] = acc[i][j][r] + bz;
          } else {
            for (int r = 0; r < 4; ++r)
              ((u16*)Cp)[(size_t)(rowb + r) * ldc + col] = f2bf(acc[i][j][r]);
          }
        }
      }
    }
  }
#undef STAGE_B
}

// ---------------------------------------------------------------------------
// Branch 1 body: local window attention. One block per (b, window); wave=head.
// LDS: qs/ks [4][64][32] (d padded to 32 w/ zeros), vt [4][32][72] = V^T,
// pm [4][64][72] (P in A-layout) aliased over qs+ks.
// ---------------------------------------------------------------------------
__device__ __forceinline__ void attn_local_body(u16* sm, int blk, int tid,
                                                const u16* __restrict__ qkv,
                                                const float* __restrict__ pos1,
                                                u16* __restrict__ attn) {
  u16* qs = sm;           // 8192 shorts
  u16* ks = sm + 8192;    // 8192 shorts
  u16* vt = sm + 18432;   // 9216 shorts
  u16* pm = sm;           // 18432 shorts, aliases qs+ks
  const int b = blk >> 4, win = blk & 15;
  const int wy = win >> 2, wx = win & 3;
  const int base_s = (b * 32 + wy * 8) * 32 + wx * 8;
  // stage q,k (ushort4-vectorized, 28 = 7*4)
  for (int idx = tid; idx < 3584; idx += 256) {
    const int mtx = idx / 1792;
    int rem = idx - mtx * 1792;
    const int h = rem / 448; rem -= h * 448;
    const int t = rem / 7;
    const int c4 = rem - t * 7;
    const int s = base_s + (t >> 3) * 32 + (t & 7);
    const ushort4 v = *(const ushort4*)(qkv + (size_t)s * 672 + mtx * 224 + h * 28 + c4 * 4);
    *(ushort4*)((mtx ? ks : qs) + (h * 64 + t) * 32 + c4 * 4) = v;
  }
  // zero k-pad cols 28..31 of q,k
  for (int idx = tid; idx < 512; idx += 256) {
    const int mtx = idx >> 8;
    const int h = (idx >> 6) & 3, t = idx & 63;
    const ushort4 z = {0, 0, 0, 0};
    *(ushort4*)((mtx ? ks : qs) + (h * 64 + t) * 32 + 28) = z;
  }
  // stage v transposed -> vt[h][d][t]
  for (int idx = tid; idx < 1792; idx += 256) {
    const int h = idx / 448;
    int rem = idx - h * 448;
    const int t = rem / 7;
    const int c4 = rem - t * 7;
    const int s = base_s + (t >> 3) * 32 + (t & 7);
    const ushort4 v = *(const ushort4*)(qkv + (size_t)s * 672 + 448 + h * 28 + c4 * 4);
    u16* col = vt + (h * 32 + c4 * 4) * 72 + t;
    col[0] = v.x; col[72] = v.y; col[144] = v.z; col[216] = v.w;
  }
  __syncthreads();
  const int h = tid >> 6, lane = tid & 63;
  const int c16 = lane & 15, g = lane >> 4;
  s8v af[4], bf[4];
  for (int t = 0; t < 4; ++t) af[t] = *(const s8v*)&qs[(h * 64 + t * 16 + c16) * 32 + g * 8];
  for (int t = 0; t < 4; ++t) bf[t] = *(const s8v*)&ks[(h * 64 + t * 16 + c16) * 32 + g * 8];
  const f4v fz = {0.f, 0.f, 0.f, 0.f};
  f4v sc[4][4];
  for (int i = 0; i < 4; ++i)
    for (int j = 0; j < 4; ++j)
      sc[i][j] = MFMA16(af[i], bf[j], fz);
  float lrow[4][4];
  const float* ph = pos1 + h * 4096;
  for (int i = 0; i < 4; ++i) {
    for (int r = 0; r < 4; ++r) {
      const int irow = i * 16 + g * 4 + r;
      float mx = -1e30f;
      for (int j = 0; j < 4; ++j) {
        const float v = sc[i][j][r] * SCALE + ph[irow * 64 + j * 16 + c16];
        sc[i][j][r] = v;
        mx = fmaxf(mx, v);
      }
      for (int d = 1; d < 16; d <<= 1) mx = fmaxf(mx, __shfl_xor(mx, d, 64));
      float sum = 0.f;
      for (int j = 0; j < 4; ++j) {
        const float e = __expf(sc[i][j][r] - mx);
        sc[i][j][r] = e;
        sum += e;
      }
      for (int d = 1; d < 16; d <<= 1) sum += __shfl_xor(sum, d, 64);
      lrow[i][r] = sum;
    }
  }
  __syncthreads();   // qs/ks frag reads done before pm (aliased) written
  for (int i = 0; i < 4; ++i)
    for (int r = 0; r < 4; ++r) {
      const int irow = i * 16 + g * 4 + r;
      for (int j = 0; j < 4; ++j)
        pm[(h * 64 + irow) * 72 + j * 16 + c16] = f2bf(sc[i][j][r]);
    }
  f4v o[4][2] = {};
  for (int kk = 0; kk < 2; ++kk) {
    s8v ap[4], bv[2];
    for (int t = 0; t < 4; ++t)
      ap[t] = *(const s8v*)&pm[(h * 64 + t * 16 + c16) * 72 + kk * 32 + g * 8];
    for (int t = 0; t < 2; ++t)
      bv[t] = *(const s8v*)&vt[(h * 32 + t * 16 + c16) * 72 + kk * 32 + g * 8];
    for (int i = 0; i < 4; ++i)
      for (int j = 0; j < 2; ++j)
        o[i][j] = MFMA16(ap[i], bv[j], o[i][j]);
  }
  for (int i = 0; i < 4; ++i)
    for (int r = 0; r < 4; ++r) {
      const int irow = i * 16 + g * 4 + r;
      const int s = base_s + (irow >> 3) * 32 + (irow & 7);
      const float inv = 1.f / lrow[i][r];
      for (int j = 0; j < 2; ++j) {
        const int d = j * 16 + c16;
        if (d < 28)
          attn[(size_t)s * 224 + h * 28 + d] = f2bf(o[i][j][r] * inv);
      }
    }
}

// ---------------------------------------------------------------------------
// Branch 2 body: cross-window attention, LDS-staged (R2 version).
// LDS: qs 16K + ks 16K + vt 16K + p2 4K = 53248 B.
// ---------------------------------------------------------------------------
__device__ __forceinline__ void attn_global_body(u16* smg, int blk, int tid,
                                                 const u16* __restrict__ qkv,
                                                 const float* __restrict__ pos2,
                                                 u16* __restrict__ attn) {
  u16* qs = smg;            // [4][4][16][32] = 8192 u16
  u16* ks = smg + 8192;
  u16* vt = smg + 16384;    // [4][4][32][16]
  u16* p2 = smg + 24576;    // [4][16][32]
  const int b = blk >> 4, ig = blk & 15;
  // ---- staging: 3 segs x 64 (w,j) rows x 28 ushort4
  for (int idx = tid; idx < 5376; idx += 256) {
    const int seg = idx / 1792;
    int rem = idx - seg * 1792;
    const int row = rem / 28;
    const int c4 = rem - row * 28;
    const int w = row >> 4, j = row & 15;
    const int ii = ig * 4 + w;
    const int y = ii >> 3, x = ii & 7;
    const int s = (b * 32 + (j >> 2) * 8 + y) * 32 + (j & 3) * 8 + x;
    const int hq = c4 / 7, d4 = c4 - hq * 7;
    const ushort4 v = *(const ushort4*)(qkv + (size_t)s * 672 + 112 + seg * 224 + c4 * 4);
    if (seg < 2) {
      *(ushort4*)((seg ? ks : qs) + ((w * 4 + hq) * 16 + j) * 32 + d4 * 4) = v;
    } else {
      u16* col = vt + ((w * 4 + hq) * 32 + d4 * 4) * 16 + j;
      col[0] = v.x; col[16] = v.y; col[32] = v.z; col[48] = v.w;
    }
  }
  for (int idx = tid; idx < 512; idx += 256) {
    const ushort4 z = {0, 0, 0, 0};
    *(ushort4*)(((idx & 256) ? ks : qs) + (idx & 255) * 32 + 28) = z;
  }
  {
    const ushort4 z = {0, 0, 0, 0};
    const int w = tid >> 6, hq = (tid >> 4) & 3;
    const int dd = 28 + ((tid >> 2) & 3), j4 = tid & 3;
    *(ushort4*)(vt + ((w * 4 + hq) * 32 + dd) * 16 + j4 * 4) = z;
  }
  __syncthreads();
  const int w = tid >> 6, lane = tid & 63;
  const int c16 = lane & 15, g = lane >> 4;
  const int i = ig * 4 + w;
  const int y = i >> 3, x = i & 7;
  const int w4 = w * 4;
  const f4v fz = {0.f, 0.f, 0.f, 0.f};
  for (int h = 0; h < 4; ++h) {
    const s8v aq = *(const s8v*)&qs[((w4 + h) * 16 + c16) * 32 + g * 8];
    const s8v bk = *(const s8v*)&ks[((w4 + h) * 16 + c16) * 32 + g * 8];
    const f4v s = MFMA16(aq, bk, fz);
    const float* ph = pos2 + h * 256;
    float l[4];
    for (int r = 0; r < 4; ++r) {
      const float v = s[r] * SCALE + ph[(g * 4 + r) * 16 + c16];
      float mx = v;
      for (int d = 1; d < 16; d <<= 1) mx = fmaxf(mx, __shfl_xor(mx, d, 64));
      const float e = __expf(v - mx);
      float sum = e;
      for (int d = 1; d < 16; d <<= 1) sum += __shfl_xor(sum, d, 64);
      l[r] = sum;
      p2[(w * 16 + g * 4 + r) * 32 + c16] = f2bf(e);
      p2[(w * 16 + g * 4 + r) * 32 + c16 + 16] = 0;   // K pad
    }
    const s8v ap = *(const s8v*)&p2[(w * 16 + c16) * 32 + g * 8];  // same-wave RAW
    f4v o[2];
    for (int nt = 0; nt < 2; ++nt) {
      s8v bv = {0, 0, 0, 0, 0, 0, 0, 0};
      if (g < 2)
        bv = *(const s8v*)&vt[((w4 + h) * 32 + nt * 16 + c16) * 16 + g * 8];
      o[nt] = MFMA16(ap, bv, fz);
    }
    for (int nt = 0; nt < 2; ++nt)
      for (int r = 0; r < 4; ++r) {
        const int d = nt * 16 + c16;
        if (d < 28) {
          const int wi = g * 4 + r;
          const int sw = (b * 32 + (wi >> 2) * 8 + y) * 32 + (wi & 3) * 8 + x;
          attn[(size_t)sw * 224 + 112 + h * 28 + d] = f2bf(o[nt][r] / l[r]);
        }
      }
  }
}

// ---------------------------------------------------------------------------
// Fused attention: blocks 0..2047 = local windows, 2048..4095 = cross-window.
// The two branches touch disjoint qkv columns and disjoint attn halves; both
// are latency-bound -> co-residency overlaps their stalls instead of running
// them back-to-back. LDS = max(55296, 53248) = 55296 -> 2 blocks/CU.
// ---------------------------------------------------------------------------
__global__ __launch_bounds__(256) void attn_fused(const u16* __restrict__ qkv,
                                                  const float* __restrict__ pos1,
                                                  const float* __restrict__ pos2,
                                                  u16* __restrict__ attn) {
  extern __shared__ u16 sm[];
  const int blk = blockIdx.x;
  const int tid = threadIdx.x;
  if (blk < 2048)
    attn_local_body(sm, blk, tid, qkv, pos1, attn);
  else
    attn_global_body(sm, blk - 2048, tid, qkv, pos2, attn);
}

// ---------------------------------------------------------------------------
// ws layout (bytes):
//   qkv   @ 0          : 131072*672*2 = 176,160,768
//   attn  @ 176160768  : 131072*224*2 =  58,720,256
//   wqkvt @ 234881024  : 768*224*2    =     344,064
//   woutt @ 235225088  : 256*224*2    =     114,688
// total ~224.5 MB
// ---------------------------------------------------------------------------
extern "C" void kernel_launch(void* const* d_in, const int* in_sizes, int n_in,
                              void* d_out, int out_size, void* d_ws, size_t ws_size,
                              hipStream_t stream) {
  const float* x    = (const float*)d_in[0];
  const float* Wq   = (const float*)d_in[1];
  const float* Wkv  = (const float*)d_in[2];
  const float* Wout = (const float*)d_in[3];
  const float* bout = (const float*)d_in[4];
  const float* pos1 = (const float*)d_in[5];
  const float* pos2 = (const float*)d_in[6];
  char* ws = (char*)d_ws;
  u16* qkv   = (u16*)ws;
  u16* attn  = (u16*)(ws + 176160768);
  u16* wqkvt = (u16*)(ws + 234881024);
  u16* woutt = (u16*)(ws + 235225088);

  prep_kernel<<<dim3(128), 256, 0, stream>>>(Wq, Wkv, Wout, wqkvt, woutt);

  // qkv = x @ [Wq|Wkv]  (A = x f32, cast fused into LDS staging; N=672)
  gemm_af<1, 0, 6><<<dim3(1024), 256, 73728, stream>>>(x, wqkvt, qkv, nullptr, 672, 672);

  attn_fused<<<dim3(4096), 256, 55296, stream>>>(qkv, pos1, pos2, attn);

  // out = attn @ Wout + bout (A = attn bf16; f32 out, N=224 -> 2 n-tiles)
  gemm_af<0, 1, 2><<<dim3(1024), 256, 73728, stream>>>(attn, woutt, d_out, bout, 224, 224);
}

// Round 6
// 385.782 us; speedup vs baseline: 1.3322x; 1.1139x over previous
//
#include <hip/hip_runtime.h>
#include <stdint.h>

typedef short s8v __attribute__((ext_vector_type(8)));
typedef float f4v __attribute__((ext_vector_type(4)));
typedef unsigned short u16;

#define MFMA16(a, b, c) __builtin_amdgcn_mfma_f32_16x16x32_bf16(a, b, c, 0, 0, 0)
#define SCALE 0.1889822365046136f

__device__ __forceinline__ u16 f2bf(float f) {
  union { float f; uint32_t u; } v;
  v.f = f;
  uint32_t u = v.u;
  u += 0x7fffu + ((u >> 16) & 1u);   // RNE
  return (u16)(u >> 16);
}

__device__ __forceinline__ void gld_lds16(const void* g, void* l) {
  __builtin_amdgcn_global_load_lds(
      (const __attribute__((address_space(1))) void*)g,
      (__attribute__((address_space(3))) void*)l, 16, 0, 0);
}

// ---------------------------------------------------------------------------
// prep: weights only (x cast fused into gemm1's A staging).
// ---------------------------------------------------------------------------
__global__ void prep_kernel(const float* __restrict__ Wq,
                            const float* __restrict__ Wkv,
                            const float* __restrict__ Wout,
                            u16* __restrict__ wqkvt,
                            u16* __restrict__ woutt) {
  const int gsz = gridDim.x * blockDim.x;
  const int gt = blockIdx.x * blockDim.x + threadIdx.x;
  for (int i = gt; i < 768 * 224; i += gsz) {
    const int n = i / 224, k = i - n * 224;
    float v = 0.f;
    if (n < 224) v = Wq[k * 224 + n];
    else if (n < 672) v = Wkv[k * 448 + (n - 224)];
    wqkvt[i] = f2bf(v);
  }
  for (int i = gt; i < 256 * 224; i += gsz) {
    const int n = i / 224, k = i - n * 224;
    const float v = (n < 224) ? Wout[k * 224 + n] : 0.f;
    woutt[i] = f2bf(v);
  }
}

// ---------------------------------------------------------------------------
// A-persistent GEMM (unchanged from R5): C[M][N] = A[M][224] * Bt[N][224]^T.
// 128-row M-tile, A staged once into LDS (f32 path: coalesced float4 + in-reg
// RNE cast); B subtiles [128][32] gld_lds dbuf, distance-2, 1 barrier/step.
// ---------------------------------------------------------------------------
template <int A_F32, int OUT_F32, int NTILES>
__global__ __launch_bounds__(256) void gemm_af(const void* __restrict__ Ap,
                                               const u16* __restrict__ Bt,
                                               void* __restrict__ Cp,
                                               const float* __restrict__ bias,
                                               int Nvalid, int ldc) {
  extern __shared__ u16 smem[];
  u16* As  = smem;            // [128][224] = 57344 B
  u16* Bs0 = smem + 28672;    // [128][32] = 8192 B
  u16* Bs1 = smem + 32768;
  const int tid = threadIdx.x;
  const int wave = tid >> 6, lane = tid & 63;
  const int c16 = lane & 15, g = lane >> 4;
  const int m0 = blockIdx.x * 128;
  const int wm = wave & 1, wn = wave >> 1;

  const int fbw = wave * 1024 + lane * 16;
  const int brow0 = fbw >> 6, bcol0 = (fbw & 63) >> 1;

#define STAGE_B(ntile, ktile, bufp)                                            \
  do {                                                                         \
    char* bb = (char*)((bufp) ? Bs1 : Bs0) + wave * 1024;                      \
    const u16* src =                                                           \
        Bt + (size_t)((ntile) * 128 + brow0) * 224 + (ktile) * 32 + bcol0;     \
    gld_lds16(src, bb);                                                        \
    gld_lds16(src + (size_t)64 * 224, bb + 4096);                              \
  } while (0)

  STAGE_B(0, 0, 0);
  if (NTILES * 7 > 1) STAGE_B(0, 1, 1);

  if (A_F32) {
    const float* Af = (const float*)Ap + (size_t)m0 * 224;
#pragma unroll
    for (int rnd = 0; rnd < 28; ++rnd) {
      const int e0 = rnd * 1024 + tid * 4;
      const float4 v = *(const float4*)(Af + e0);
      ushort4 o;
      o.x = f2bf(v.x); o.y = f2bf(v.y); o.z = f2bf(v.z); o.w = f2bf(v.w);
      *(ushort4*)(As + e0) = o;
    }
  } else {
    for (int rnd = 0; rnd < 14; ++rnd) {
      const int fb = rnd * 4096 + fbw;
      const int row = fb / 448;
      const int off = fb - row * 448;
      gld_lds16((const u16*)Ap + (size_t)(m0 + row) * 224 + (off >> 1),
                (char*)As + rnd * 4096 + wave * 1024);
    }
  }

  __syncthreads();

  for (int nt = 0; nt < NTILES; ++nt) {
    f4v acc[4][4] = {};
    for (int kt = 0; kt < 7; ++kt) {
      const int t = nt * 7 + kt;
      const u16* Bs = (t & 1) ? Bs1 : Bs0;
      s8v af[4], bf[4];
      for (int tt = 0; tt < 4; ++tt)
        af[tt] = *(const s8v*)&As[(wm * 64 + tt * 16 + c16) * 224 + kt * 32 + g * 8];
      for (int tt = 0; tt < 4; ++tt)
        bf[tt] = *(const s8v*)&Bs[(wn * 64 + tt * 16 + c16) * 32 + g * 8];
      for (int i = 0; i < 4; ++i)
        for (int j = 0; j < 4; ++j)
          acc[i][j] = MFMA16(af[i], bf[j], acc[i][j]);
      __syncthreads();
      const int ns = t + 2;
      if (ns < NTILES * 7) {
        const int nnt = ns / 7;
        STAGE_B(nnt, ns - nnt * 7, t & 1);
      }
    }
    const int n0 = nt * 128;
    for (int i = 0; i < 4; ++i) {
      const int rowb = m0 + wm * 64 + i * 16 + g * 4;
      for (int j = 0; j < 4; ++j) {
        const int col = n0 + wn * 64 + j * 16 + c16;
        if (col < Nvalid) {
          if (OUT_F32) {
            const float bz = bias[col];
            for (int r = 0; r < 4; ++r)
              ((float*)Cp)[(size_t)(rowb + r) * ldc + col] = acc[i][j][r] + bz;
          } else {
            for (int r = 0; r < 4; ++r)
              ((u16*)Cp)[(size_t)(rowb + r) * ldc + col] = f2bf(acc[i][j][r]);
          }
        }
      }
    }
  }
#undef STAGE_B
}

// ---------------------------------------------------------------------------
// Branch 1 body: local window attention. One block per (b, window); wave=head.
// Staging rewritten division-light + unrolled so loads batch:
//  - q/k: same idx->(mtx,h,t,c4) mapping as before, computed via ONE magic
//    div by 7 (1792 = 7*256, 448 = 7*64).
//  - v: lane=t mapping (zero divisions); writes vt[h][d][72] at consecutive
//    u16 per lane -> conflict-free (was 4-way). Global reads become 8B/lane
//    scatters over 64 rows, but the per-block V working set (28 KB) is
//    L1-resident across the 7 unrolled iterations.
// ---------------------------------------------------------------------------
__device__ __forceinline__ void attn_local_body(u16* sm, int blk, int tid,
                                                const u16* __restrict__ qkv,
                                                const float* __restrict__ pos1,
                                                u16* __restrict__ attn) {
  u16* qs = sm;           // 8192 shorts
  u16* ks = sm + 8192;    // 8192 shorts
  u16* vt = sm + 18432;   // 9216 shorts
  u16* pm = sm;           // 18432 shorts, aliases qs+ks
  const int b = blk >> 4, win = blk & 15;
  const int wy = win >> 2, wx = win & 3;
  const int base_s = (b * 32 + wy * 8) * 32 + wx * 8;
  // stage q,k: 3584 ushort4, idx = mtx*1792 + h*448 + t*7 + c4
#pragma unroll
  for (int m = 0; m < 14; ++m) {
    const int idx = m * 256 + tid;
    const int q7 = idx / 7;              // = mtx*256 + h*64 + t (magic-mul)
    const int c4 = idx - q7 * 7;
    const int t = q7 & 63, h = (q7 >> 6) & 3, mtx = q7 >> 8;
    const int s = base_s + (t >> 3) * 32 + (t & 7);
    const ushort4 v = *(const ushort4*)(qkv + (size_t)s * 672 + mtx * 224 + h * 28 + c4 * 4);
    *(ushort4*)((mtx ? ks : qs) + (h * 64 + t) * 32 + c4 * 4) = v;
  }
  // zero k-pad cols 28..31 of q,k
#pragma unroll
  for (int m = 0; m < 2; ++m) {
    const int idx = m * 256 + tid;
    const int mtx = idx >> 8;
    const int h = (idx >> 6) & 3, t = idx & 63;
    const ushort4 z = {0, 0, 0, 0};
    *(ushort4*)((mtx ? ks : qs) + (h * 64 + t) * 32 + 28) = z;
  }
  // stage v transposed -> vt[h][d][t]; lane = t, head = wave, loop c4.
  {
    const int t = tid & 63, wq = tid >> 6;
    const int s = base_s + (t >> 3) * 32 + (t & 7);
    const u16* vrow = qkv + (size_t)s * 672 + 448 + wq * 28;
    u16* vcolbase = vt + (wq * 32) * 72 + t;
#pragma unroll
    for (int c4 = 0; c4 < 7; ++c4) {
      const ushort4 v = *(const ushort4*)(vrow + c4 * 4);
      u16* col = vcolbase + (c4 * 4) * 72;
      col[0] = v.x; col[72] = v.y; col[144] = v.z; col[216] = v.w;
    }
  }
  __syncthreads();
  const int h = tid >> 6, lane = tid & 63;
  const int c16 = lane & 15, g = lane >> 4;
  s8v af[4], bf[4];
  for (int t = 0; t < 4; ++t) af[t] = *(const s8v*)&qs[(h * 64 + t * 16 + c16) * 32 + g * 8];
  for (int t = 0; t < 4; ++t) bf[t] = *(const s8v*)&ks[(h * 64 + t * 16 + c16) * 32 + g * 8];
  const f4v fz = {0.f, 0.f, 0.f, 0.f};
  f4v sc[4][4];
  for (int i = 0; i < 4; ++i)
    for (int j = 0; j < 4; ++j)
      sc[i][j] = MFMA16(af[i], bf[j], fz);
  float lrow[4][4];
  const float* ph = pos1 + h * 4096;
  for (int i = 0; i < 4; ++i) {
    for (int r = 0; r < 4; ++r) {
      const int irow = i * 16 + g * 4 + r;
      float mx = -1e30f;
      for (int j = 0; j < 4; ++j) {
        const float v = sc[i][j][r] * SCALE + ph[irow * 64 + j * 16 + c16];
        sc[i][j][r] = v;
        mx = fmaxf(mx, v);
      }
      for (int d = 1; d < 16; d <<= 1) mx = fmaxf(mx, __shfl_xor(mx, d, 64));
      float sum = 0.f;
      for (int j = 0; j < 4; ++j) {
        const float e = __expf(sc[i][j][r] - mx);
        sc[i][j][r] = e;
        sum += e;
      }
      for (int d = 1; d < 16; d <<= 1) sum += __shfl_xor(sum, d, 64);
      lrow[i][r] = sum;
    }
  }
  __syncthreads();   // qs/ks frag reads done before pm (aliased) written
  for (int i = 0; i < 4; ++i)
    for (int r = 0; r < 4; ++r) {
      const int irow = i * 16 + g * 4 + r;
      for (int j = 0; j < 4; ++j)
        pm[(h * 64 + irow) * 72 + j * 16 + c16] = f2bf(sc[i][j][r]);
    }
  f4v o[4][2] = {};
  for (int kk = 0; kk < 2; ++kk) {
    s8v ap[4], bv[2];
    for (int t = 0; t < 4; ++t)
      ap[t] = *(const s8v*)&pm[(h * 64 + t * 16 + c16) * 72 + kk * 32 + g * 8];
    for (int t = 0; t < 2; ++t)
      bv[t] = *(const s8v*)&vt[(h * 32 + t * 16 + c16) * 72 + kk * 32 + g * 8];
    for (int i = 0; i < 4; ++i)
      for (int j = 0; j < 2; ++j)
        o[i][j] = MFMA16(ap[i], bv[j], o[i][j]);
  }
  for (int i = 0; i < 4; ++i)
    for (int r = 0; r < 4; ++r) {
      const int irow = i * 16 + g * 4 + r;
      const int s = base_s + (irow >> 3) * 32 + (irow & 7);
      const float inv = 1.f / lrow[i][r];
      for (int j = 0; j < 2; ++j) {
        const int d = j * 16 + c16;
        if (d < 28)
          attn[(size_t)s * 224 + h * 28 + d] = f2bf(o[i][j][r] * inv);
      }
    }
}

// ---------------------------------------------------------------------------
// Branch 2 body: cross-window attention, LDS-staged.
// Staging rewritten:
//  - q/k: same mapping, single magic div by 7 (1792=7*256, 28=4*7), unrolled.
//  - vt: lane=(w,j), loop (hq,d4); w-stride padded 2048->2056 u16 so write
//    banks = 4w + j/2 (<=2-way; was a 28-way single-bank pileup). Reads keep
//    16B alignment (w*2056 u16 = 257*16 B).
// LDS: qs 16K + ks 16K + vt 16448 + p2 4K = 53312 B.
// ---------------------------------------------------------------------------
__device__ __forceinline__ void attn_global_body(u16* smg, int blk, int tid,
                                                 const u16* __restrict__ qkv,
                                                 const float* __restrict__ pos2,
                                                 u16* __restrict__ attn) {
  u16* qs = smg;            // [4][4][16][32] = 8192 u16
  u16* ks = smg + 8192;
  u16* vt = smg + 16384;    // [4] w-stride 2056: [4][32][16] + 8 pad
  u16* p2 = smg + 24608;    // [4][16][32]
  const int b = blk >> 4, ig = blk & 15;
  // ---- stage q,k: 3584 ushort4, idx = seg*1792 + (w*16+j)*28 + hq*7 + d4
#pragma unroll
  for (int m = 0; m < 14; ++m) {
    const int idx = m * 256 + tid;
    const int q7 = idx / 7;              // = seg*256 + (w*16+j)*4 + hq
    const int d4 = idx - q7 * 7;
    const int hq = q7 & 3, row = (q7 >> 2) & 63, seg = q7 >> 8;
    const int w = row >> 4, j = row & 15;
    const int ii = ig * 4 + w;
    const int y = ii >> 3, x = ii & 7;
    const int s = (b * 32 + (j >> 2) * 8 + y) * 32 + (j & 3) * 8 + x;
    const ushort4 v =
        *(const ushort4*)(qkv + (size_t)s * 672 + 112 + seg * 224 + hq * 28 + d4 * 4);
    *(ushort4*)((seg ? ks : qs) + ((w * 4 + hq) * 16 + j) * 32 + hq * 0 + d4 * 4) = v;
  }
  // ---- stage v transposed: lane=(w,j), loop c4 = wq..27 step 4
  {
    const int j = tid & 15, w = (tid >> 4) & 3, wq = tid >> 6;
    const int ii = ig * 4 + w;
    const int y = ii >> 3, x = ii & 7;
    const int s = (b * 32 + (j >> 2) * 8 + y) * 32 + (j & 3) * 8 + x;
    const u16* vrow = qkv + (size_t)s * 672 + 560;
    u16* vbase = vt + w * 2056 + j;
#pragma unroll
    for (int c4o = 0; c4o < 7; ++c4o) {
      const int c4 = c4o * 4 + wq;       // 0..27
      const int hq = c4 / 7;             // magic-mul
      const int d4 = c4 - hq * 7;
      const ushort4 v = *(const ushort4*)(vrow + c4 * 4);
      u16* col = vbase + (hq * 32 + d4 * 4) * 16;
      col[0] = v.x; col[16] = v.y; col[32] = v.z; col[48] = v.w;
    }
  }
  // zero d-pad 28..31 of qs/ks and vt rows 28..31
#pragma unroll
  for (int m = 0; m < 2; ++m) {
    const int idx = m * 256 + tid;
    const ushort4 z = {0, 0, 0, 0};
    *(ushort4*)(((idx & 256) ? ks : qs) + (idx & 255) * 32 + 28) = z;
  }
  {
    const ushort4 z = {0, 0, 0, 0};
    const int w = tid >> 6, hq = (tid >> 4) & 3;
    const int dd = 28 + ((tid >> 2) & 3), j4 = tid & 3;
    *(ushort4*)(vt + w * 2056 + (hq * 32 + dd) * 16 + j4 * 4) = z;
  }
  __syncthreads();
  const int w = tid >> 6, lane = tid & 63;
  const int c16 = lane & 15, g = lane >> 4;
  const int i = ig * 4 + w;
  const int y = i >> 3, x = i & 7;
  const int w4 = w * 4;
  const f4v fz = {0.f, 0.f, 0.f, 0.f};
  for (int h = 0; h < 4; ++h) {
    const s8v aq = *(const s8v*)&qs[((w4 + h) * 16 + c16) * 32 + g * 8];
    const s8v bk = *(const s8v*)&ks[((w4 + h) * 16 + c16) * 32 + g * 8];
    const f4v s = MFMA16(aq, bk, fz);
    const float* ph = pos2 + h * 256;
    float l[4];
    for (int r = 0; r < 4; ++r) {
      const float v = s[r] * SCALE + ph[(g * 4 + r) * 16 + c16];
      float mx = v;
      for (int d = 1; d < 16; d <<= 1) mx = fmaxf(mx, __shfl_xor(mx, d, 64));
      const float e = __expf(v - mx);
      float sum = e;
      for (int d = 1; d < 16; d <<= 1) sum += __shfl_xor(sum, d, 64);
      l[r] = sum;
      p2[(w * 16 + g * 4 + r) * 32 + c16] = f2bf(e);
      p2[(w * 16 + g * 4 + r) * 32 + c16 + 16] = 0;   // K pad
    }
    const s8v ap = *(const s8v*)&p2[(w * 16 + c16) * 32 + g * 8];  // same-wave RAW
    f4v o[2];
    for (int nt = 0; nt < 2; ++nt) {
      s8v bv = {0, 0, 0, 0, 0, 0, 0, 0};
      if (g < 2)
        bv = *(const s8v*)&vt[w * 2056 + (h * 32 + nt * 16 + c16) * 16 + g * 8];
      o[nt] = MFMA16(ap, bv, fz);
    }
    for (int nt = 0; nt < 2; ++nt)
      for (int r = 0; r < 4; ++r) {
        const int d = nt * 16 + c16;
        if (d < 28) {
          const int wi = g * 4 + r;
          const int sw = (b * 32 + (wi >> 2) * 8 + y) * 32 + (wi & 3) * 8 + x;
          attn[(size_t)sw * 224 + 112 + h * 28 + d] = f2bf(o[nt][r] / l[r]);
        }
      }
  }
}

// ---------------------------------------------------------------------------
// Fused attention: blocks 0..2047 = local windows, 2048..4095 = cross-window.
// LDS = max(55296, 53312) = 55296 -> 2 blocks/CU.
// ---------------------------------------------------------------------------
__global__ __launch_bounds__(256) void attn_fused(const u16* __restrict__ qkv,
                                                  const float* __restrict__ pos1,
                                                  const float* __restrict__ pos2,
                                                  u16* __restrict__ attn) {
  extern __shared__ u16 sm[];
  const int blk = blockIdx.x;
  const int tid = threadIdx.x;
  if (blk < 2048)
    attn_local_body(sm, blk, tid, qkv, pos1, attn);
  else
    attn_global_body(sm, blk - 2048, tid, qkv, pos2, attn);
}

// ---------------------------------------------------------------------------
// ws layout (bytes):
//   qkv   @ 0          : 131072*672*2 = 176,160,768
//   attn  @ 176160768  : 131072*224*2 =  58,720,256
//   wqkvt @ 234881024  : 768*224*2    =     344,064
//   woutt @ 235225088  : 256*224*2    =     114,688
// ---------------------------------------------------------------------------
extern "C" void kernel_launch(void* const* d_in, const int* in_sizes, int n_in,
                              void* d_out, int out_size, void* d_ws, size_t ws_size,
                              hipStream_t stream) {
  const float* x    = (const float*)d_in[0];
  const float* Wq   = (const float*)d_in[1];
  const float* Wkv  = (const float*)d_in[2];
  const float* Wout = (const float*)d_in[3];
  const float* bout = (const float*)d_in[4];
  const float* pos1 = (const float*)d_in[5];
  const float* pos2 = (const float*)d_in[6];
  char* ws = (char*)d_ws;
  u16* qkv   = (u16*)ws;
  u16* attn  = (u16*)(ws + 176160768);
  u16* wqkvt = (u16*)(ws + 234881024);
  u16* woutt = (u16*)(ws + 235225088);

  prep_kernel<<<dim3(128), 256, 0, stream>>>(Wq, Wkv, Wout, wqkvt, woutt);

  // qkv = x @ [Wq|Wkv]  (A = x f32, cast fused into LDS staging; N=672)
  gemm_af<1, 0, 6><<<dim3(1024), 256, 73728, stream>>>(x, wqkvt, qkv, nullptr, 672, 672);

  attn_fused<<<dim3(4096), 256, 55296, stream>>>(qkv, pos1, pos2, attn);

  // out = attn @ Wout + bout (A = attn bf16; f32 out, N=224 -> 2 n-tiles)
  gemm_af<0, 1, 2><<<dim3(1024), 256, 73728, stream>>>(attn, woutt, d_out, bout, 224, 224);
}